// Round 2
// baseline (724.331 us; speedup 1.0000x reference)
//
#include <hip/hip_runtime.h>

#define TOK  4096
#define INF  4096
#define OUTF 11008
#define NG   704512   // number of quant groups
#define QD   172      // OUTF / 64

typedef __bf16 bf16x8 __attribute__((ext_vector_type(8)));
typedef float  floatx4 __attribute__((ext_vector_type(4)));

// ---------------- async global -> LDS, 16B per lane ----------------
__device__ inline void glds16(const __bf16* g, __bf16* l) {
  __builtin_amdgcn_global_load_lds(
      (const __attribute__((address_space(1))) void*)g,
      (__attribute__((address_space(3))) void*)l,
      16, 0, 0);
}

// ---------------- x (fp32) -> bf16 ----------------
__global__ __launch_bounds__(256) void convert_x_kernel(
    const float* __restrict__ x, __bf16* __restrict__ Xb) {
  size_t i = ((size_t)blockIdx.x * 256 + threadIdx.x) * 8;
  float4 a = *(const float4*)(x + i);
  float4 b = *(const float4*)(x + i + 4);
  bf16x8 o;
  o[0] = (__bf16)a.x; o[1] = (__bf16)a.y; o[2] = (__bf16)a.z; o[3] = (__bf16)a.w;
  o[4] = (__bf16)b.x; o[5] = (__bf16)b.y; o[6] = (__bf16)b.z; o[7] = (__bf16)b.w;
  *(bf16x8*)(Xb + i) = o;
}

// ---------------- dequant W_q -> bf16 Wb[OUTF][INF] ----------------
__global__ __launch_bounds__(256) void dequant_w_kernel(
    const int* __restrict__ Wq, const float* __restrict__ sc,
    const float* __restrict__ zp, __bf16* __restrict__ Wb) {
  const int b = blockIdx.x;          // 0 .. 32*172-1
  const int r = b / QD;              // 0..31
  const int q = b - r * QD;
  const int*   wrow = Wq + (size_t)r * NG + (size_t)q * INF;
  const float* srow = sc + (size_t)q * INF;
  const float* zrow = zp + (size_t)q * INF;
  __bf16* hrow = Wb + (size_t)(r * QD + q) * INF;
  __bf16* lrow = Wb + (size_t)((r + 32) * QD + q) * INF;
#pragma unroll
  for (int it = 0; it < 2; ++it) {
    const int k = ((int)threadIdx.x + it * 256) * 8;
    int4   w0 = *(const int4*)(wrow + k);
    int4   w1 = *(const int4*)(wrow + k + 4);
    float4 s0 = *(const float4*)(srow + k);
    float4 s1 = *(const float4*)(srow + k + 4);
    float4 z0 = *(const float4*)(zrow + k);
    float4 z1 = *(const float4*)(zrow + k + 4);
    bf16x8 hi, lo;
    hi[0] = (__bf16)(((float)((w0.x >> 4) & 0xF) - z0.x) * s0.x);
    hi[1] = (__bf16)(((float)((w0.y >> 4) & 0xF) - z0.y) * s0.y);
    hi[2] = (__bf16)(((float)((w0.z >> 4) & 0xF) - z0.z) * s0.z);
    hi[3] = (__bf16)(((float)((w0.w >> 4) & 0xF) - z0.w) * s0.w);
    hi[4] = (__bf16)(((float)((w1.x >> 4) & 0xF) - z1.x) * s1.x);
    hi[5] = (__bf16)(((float)((w1.y >> 4) & 0xF) - z1.y) * s1.y);
    hi[6] = (__bf16)(((float)((w1.z >> 4) & 0xF) - z1.z) * s1.z);
    hi[7] = (__bf16)(((float)((w1.w >> 4) & 0xF) - z1.w) * s1.w);
    lo[0] = (__bf16)(((float)(w0.x & 0xF) - z0.x) * s0.x);
    lo[1] = (__bf16)(((float)(w0.y & 0xF) - z0.y) * s0.y);
    lo[2] = (__bf16)(((float)(w0.z & 0xF) - z0.z) * s0.z);
    lo[3] = (__bf16)(((float)(w0.w & 0xF) - z0.w) * s0.w);
    lo[4] = (__bf16)(((float)(w1.x & 0xF) - z1.x) * s1.x);
    lo[5] = (__bf16)(((float)(w1.y & 0xF) - z1.y) * s1.y);
    lo[6] = (__bf16)(((float)(w1.z & 0xF) - z1.z) * s1.z);
    lo[7] = (__bf16)(((float)(w1.w & 0xF) - z1.w) * s1.w);
    *(bf16x8*)(hrow + k) = hi;
    *(bf16x8*)(lrow + k) = lo;
  }
}

// ---------------- 256x256 bf16 GEMM, 4-phase counted-vmcnt pipeline --------
// C[4096][11008] = Xb[4096][4096] * Wb[11008][4096]^T + bias
// 256x256 tile, BK=64, 8 waves (2M x 4N), per-wave 128x64 output, 16x16x32.
// Staging is half-granular and wave-owned: each wave stages exactly the A-half
// (rows hA*128..+127, its own 32-row slice) and B-half it reads, as 4+4
// glds16 instrs per tile, issued in pairs spread across the MFMA quadrants.
// Per-thread issue order (uniform across all threads): B0 B1 | B2 B3 | A0 A1 |
// A2 A3 for tile t+1, during tile t.  Checkpoints (never drain):
//   boundary  : vmcnt(4) -> B(t+1) landed, barrier publishes.
//   intra-P1  : vmcnt(2) -> A(t)   landed, barrier publishes (covered by bfr
//               ds_reads issued just before).
// Steady-state per-thread outstanding: 4 -> 6 -> [2] -> 4 -> 6 -> 8 -> [4].

#define QUAD(MOFF, JX)                                                       \
    _Pragma("unroll") for (int mi = 0; mi < 4; ++mi)                         \
      af[mi] = *(const bf16x8*)(A_ + aoff + ((mi + (MOFF)) << 10) + (JX));   \
    __builtin_amdgcn_s_setprio(1);                                           \
    _Pragma("unroll") for (int mi = 0; mi < 4; ++mi)                         \
      _Pragma("unroll") for (int ni = 0; ni < 4; ++ni)                       \
        acc[mi + (MOFF)][ni] = __builtin_amdgcn_mfma_f32_16x16x32_bf16(      \
            af[mi], bfr[ni], acc[mi + (MOFF)][ni], 0, 0, 0);                 \
    __builtin_amdgcn_s_setprio(0);

#define TILE(P_, Q_, T_)                                                     \
  { const __bf16* A_ = &As[P_][0];                                           \
    const __bf16* B_ = &Bs[P_][0];                                           \
    const int st_ = (T_) < 63;                                               \
    const int ks_ = ((T_) + 1) << 6;                                         \
    bf16x8 af[4], bfr[4];                                                    \
    _Pragma("unroll") for (int ni = 0; ni < 4; ++ni)                         \
      bfr[ni] = *(const bf16x8*)(B_ + boff + (ni << 10) + jx0);              \
    if (st_) { glds16(sgB[0] + ks_, lB##Q_[0]);                              \
               glds16(sgB[1] + ks_, lB##Q_[1]);                              \
               asm volatile("s_waitcnt vmcnt(2)" ::: "memory"); }            \
    else     { asm volatile("s_waitcnt vmcnt(0)" ::: "memory"); }            \
    __builtin_amdgcn_s_barrier();                                            \
    asm volatile("" ::: "memory");                                           \
    QUAD(0, jx0)                                                             \
    if (st_) { glds16(sgB[2] + ks_, lB##Q_[2]);                              \
               glds16(sgB[3] + ks_, lB##Q_[3]); }                            \
    QUAD(4, jx0)                                                             \
    if (st_) { glds16(sgA[0] + ks_, lA##Q_[0]);                              \
               glds16(sgA[1] + ks_, lA##Q_[1]); }                            \
    _Pragma("unroll") for (int ni = 0; ni < 4; ++ni)                         \
      bfr[ni] = *(const bf16x8*)(B_ + boff + (ni << 10) + jx1);              \
    QUAD(0, jx1)                                                             \
    if (st_) { glds16(sgA[2] + ks_, lA##Q_[2]);                              \
               glds16(sgA[3] + ks_, lA##Q_[3]); }                            \
    QUAD(4, jx1)                                                             \
    if (st_) { asm volatile("s_waitcnt vmcnt(4)" ::: "memory");              \
               __builtin_amdgcn_s_barrier();                                 \
               asm volatile("" ::: "memory"); }                              \
  }

__global__ __launch_bounds__(512, 2) void gemm_bt(
    const __bf16* __restrict__ Xb, const __bf16* __restrict__ Wb,
    const float* __restrict__ bias, float* __restrict__ out) {
  __shared__ __align__(16) __bf16 As[2][256 * 64];
  __shared__ __align__(16) __bf16 Bs[2][256 * 64];

  const int tid  = threadIdx.x;
  const int wave = tid >> 6;
  const int lane = tid & 63;

  // XCD-rectangular swizzle: hw assigns XCD = blockIdx.x % 8. Each XCD owns a
  // 16bm x 5bn band (cols 5x..5x+4), walked as two 8x4 sub-rects then the 5th
  // column; 3 leftover cols (40-42) are split 6-blocks-per-XCD. Bijective.
  // Resident set per XCD ~= 8bm x 4bn: B panels (8MB) L2-warm and reused by
  // the following sub-rect; A panels stream from L3.
  const int orig = blockIdx.x;
  const int xcd  = orig & 7;
  const int slot = orig >> 3;          // 0..85
  int bm, bn;
  if (slot < 64) {        // two 8x4 sub-rects of the band
    bm = ((slot >> 5) << 3) + (slot & 7);
    bn = xcd * 5 + ((slot >> 3) & 3);
  } else if (slot < 80) { // 5th column of the band
    bm = slot - 64;
    bn = xcd * 5 + 4;
  } else {                // shared leftover strip, cols 40..42
    const int idx = xcd * 6 + (slot - 80);   // 0..47
    bm = idx & 15;
    bn = 40 + (idx >> 4);
  }
  const int m0 = bm << 8;
  const int n0 = bn << 8;

  const int wm = (wave >> 2) << 7;   // 0 or 128
  const int wn = (wave & 3) << 6;    // 0,64,128,192

  // ---- wave-owned staging assignment ----
  // A-half hA = wave>>2 (matches the half this wave's afr reads), 32-row slice
  // u = wave&3.  B-half hB = (wave&3)>>1 (matches wn), slice v.
  const int hA = wave >> 2, u = wave & 3;
  const int hB = (wave & 3) >> 1, v = ((wave >> 2) << 1) | (wave & 1);
  const int jst = (lane & 7) ^ (lane >> 3);   // src chunk for linear LDS dest
  const __bf16* sgA[4]; const __bf16* sgB[4];
  __bf16 *lA0[4], *lA1[4], *lB0[4], *lB1[4];
#pragma unroll
  for (int i = 0; i < 4; ++i) {
    const int ra = hA * 128 + u * 32 + i * 8;   // 8 rows per glds16
    const int rb = hB * 128 + v * 32 + i * 8;
    sgA[i] = Xb + (size_t)(m0 + ra + (lane >> 3)) * INF + (jst << 3);
    sgB[i] = Wb + (size_t)(n0 + rb + (lane >> 3)) * INF + (jst << 3);
    lA0[i] = &As[0][ra << 6]; lA1[i] = &As[1][ra << 6];   // wave-uniform
    lB0[i] = &Bs[0][rb << 6]; lB1[i] = &Bs[1][rb << 6];
  }

  floatx4 acc[8][4];
  const floatx4 z4 = {0.f, 0.f, 0.f, 0.f};
#pragma unroll
  for (int mi = 0; mi < 8; ++mi)
#pragma unroll
    for (int ni = 0; ni < 4; ++ni) acc[mi][ni] = z4;

  const int fr   = lane & 15;
  const int quad = lane >> 4;
  const int jx0  = ((0 * 4 + quad) ^ (fr & 7)) << 3;
  const int jx1  = ((1 * 4 + quad) ^ (fr & 7)) << 3;
  const int aoff = (wm + fr) << 6;
  const int boff = (wn + fr) << 6;

  // prologue: tile0 (B first, then A); wait B only, A(0) stays in flight
#pragma unroll
  for (int i = 0; i < 4; ++i) glds16(sgB[i], lB0[i]);
#pragma unroll
  for (int i = 0; i < 4; ++i) glds16(sgA[i], lA0[i]);
  asm volatile("s_waitcnt vmcnt(4)" ::: "memory");
  __builtin_amdgcn_s_barrier();
  asm volatile("" ::: "memory");

  for (int t = 0; t < 64; t += 2) {
    TILE(0, 1, t)
    TILE(1, 0, t + 1)
  }

  // epilogue: C/D layout col = lane&15 (n), row = quad*4 + reg (m)
#pragma unroll
  for (int ni = 0; ni < 4; ++ni) {
    const int n = n0 + wn + (ni << 4) + fr;
    const float bv = bias[n];
#pragma unroll
    for (int mi = 0; mi < 8; ++mi) {
      const int mb = m0 + wm + (mi << 4) + (quad << 2);
#pragma unroll
      for (int j = 0; j < 4; ++j) {
        out[(size_t)(mb + j) * OUTF + n] = acc[mi][ni][j] + bv;
      }
    }
  }
}

extern "C" void kernel_launch(void* const* d_in, const int* in_sizes, int n_in,
                              void* d_out, int out_size, void* d_ws, size_t ws_size,
                              hipStream_t stream) {
  const float* x  = (const float*)d_in[0];   // [4096,4096] fp32
  const int*   Wq = (const int*)d_in[1];     // [32,704512] int32 (one byte each)
  const float* sc = (const float*)d_in[2];   // [704512]
  const float* zp = (const float*)d_in[3];   // [704512]
  const float* bs = (const float*)d_in[4];   // [11008]
  float* out = (float*)d_out;                // [4096,11008] fp32

  __bf16* Xb = (__bf16*)d_ws;                       // 32 MiB
  __bf16* Wb = Xb + (size_t)TOK * INF;              // 86 MiB

  convert_x_kernel<<<dim3((TOK * INF) / (256 * 8)), dim3(256), 0, stream>>>(x, Xb);
  dequant_w_kernel<<<dim3(32 * QD), dim3(256), 0, stream>>>(Wq, sc, zp, Wb);
  gemm_bt<<<dim3(OUTF / 256 * (TOK / 256)), dim3(512), 0, stream>>>(Xb, Wb, bs, out);
}

// Round 4
// 670.643 us; speedup vs baseline: 1.0801x; 1.0801x over previous
//
#include <hip/hip_runtime.h>

#define TOK  4096
#define INF  4096
#define OUTF 11008
#define NG   704512   // number of quant groups
#define QD   172      // OUTF / 64

typedef __bf16 bf16x8 __attribute__((ext_vector_type(8)));
typedef float  floatx4 __attribute__((ext_vector_type(4)));

// ---------------- async global -> LDS, 16B per lane ----------------
__device__ inline void glds16(const __bf16* g, __bf16* l) {
  __builtin_amdgcn_global_load_lds(
      (const __attribute__((address_space(1))) void*)g,
      (__attribute__((address_space(3))) void*)l,
      16, 0, 0);
}

// ---------------- x (fp32) -> bf16 ----------------
__global__ __launch_bounds__(256) void convert_x_kernel(
    const float* __restrict__ x, __bf16* __restrict__ Xb) {
  size_t i = ((size_t)blockIdx.x * 256 + threadIdx.x) * 8;
  float4 a = *(const float4*)(x + i);
  float4 b = *(const float4*)(x + i + 4);
  bf16x8 o;
  o[0] = (__bf16)a.x; o[1] = (__bf16)a.y; o[2] = (__bf16)a.z; o[3] = (__bf16)a.w;
  o[4] = (__bf16)b.x; o[5] = (__bf16)b.y; o[6] = (__bf16)b.z; o[7] = (__bf16)b.w;
  *(bf16x8*)(Xb + i) = o;
}

// ---------------- dequant W_q -> bf16 Wb[OUTF][INF] ----------------
__global__ __launch_bounds__(256) void dequant_w_kernel(
    const int* __restrict__ Wq, const float* __restrict__ sc,
    const float* __restrict__ zp, __bf16* __restrict__ Wb) {
  const int b = blockIdx.x;          // 0 .. 32*172-1
  const int r = b / QD;              // 0..31
  const int q = b - r * QD;
  const int*   wrow = Wq + (size_t)r * NG + (size_t)q * INF;
  const float* srow = sc + (size_t)q * INF;
  const float* zrow = zp + (size_t)q * INF;
  __bf16* hrow = Wb + (size_t)(r * QD + q) * INF;
  __bf16* lrow = Wb + (size_t)((r + 32) * QD + q) * INF;
#pragma unroll
  for (int it = 0; it < 2; ++it) {
    const int k = ((int)threadIdx.x + it * 256) * 8;
    int4   w0 = *(const int4*)(wrow + k);
    int4   w1 = *(const int4*)(wrow + k + 4);
    float4 s0 = *(const float4*)(srow + k);
    float4 s1 = *(const float4*)(srow + k + 4);
    float4 z0 = *(const float4*)(zrow + k);
    float4 z1 = *(const float4*)(zrow + k + 4);
    bf16x8 hi, lo;
    hi[0] = (__bf16)(((float)((w0.x >> 4) & 0xF) - z0.x) * s0.x);
    hi[1] = (__bf16)(((float)((w0.y >> 4) & 0xF) - z0.y) * s0.y);
    hi[2] = (__bf16)(((float)((w0.z >> 4) & 0xF) - z0.z) * s0.z);
    hi[3] = (__bf16)(((float)((w0.w >> 4) & 0xF) - z0.w) * s0.w);
    hi[4] = (__bf16)(((float)((w1.x >> 4) & 0xF) - z1.x) * s1.x);
    hi[5] = (__bf16)(((float)((w1.y >> 4) & 0xF) - z1.y) * s1.y);
    hi[6] = (__bf16)(((float)((w1.z >> 4) & 0xF) - z1.z) * s1.z);
    hi[7] = (__bf16)(((float)((w1.w >> 4) & 0xF) - z1.w) * s1.w);
    lo[0] = (__bf16)(((float)(w0.x & 0xF) - z0.x) * s0.x);
    lo[1] = (__bf16)(((float)(w0.y & 0xF) - z0.y) * s0.y);
    lo[2] = (__bf16)(((float)(w0.z & 0xF) - z0.z) * s0.z);
    lo[3] = (__bf16)(((float)(w0.w & 0xF) - z0.w) * s0.w);
    lo[4] = (__bf16)(((float)(w1.x & 0xF) - z1.x) * s1.x);
    lo[5] = (__bf16)(((float)(w1.y & 0xF) - z1.y) * s1.y);
    lo[6] = (__bf16)(((float)(w1.z & 0xF) - z1.z) * s1.z);
    lo[7] = (__bf16)(((float)(w1.w & 0xF) - z1.w) * s1.w);
    *(bf16x8*)(hrow + k) = hi;
    *(bf16x8*)(lrow + k) = lo;
  }
}

// ---------------- 256x256 bf16 GEMM, 8-phase counted-vmcnt pipeline --------
// C[4096][11008] = Xb[4096][4096] * Wb[11008][4096]^T + bias
// 256x256 tile, BK=64, 8 waves (2M x 4N), per-wave 128x64, 16x16x32 MFMA.
// Per K-tile: 4 phases = (kk,mh) quadrants, each {ds_read subtile; 2x glds16
// stage; barrier; lgkmcnt(0); setprio(1); 16 MFMA; setprio(0); barrier}.
// Staging is tile-aligned into the OTHER buffer (race-free by construction),
// issue order per thread: p1 B0 B1 | p2 B2 B3 | p3 A0 A2 | p4 A1 A3.
// Counted waits, never drained mid-loop:
//   end-p4: vmcnt(2) -> publishes B0-3,A0,A2 of t+1 (A1,A3 stay in flight)
//   end-p1: vmcnt(2) -> publishes A1,A3 (rows 64-127/192-255, first read p2)
// Outstanding ledger: 2 ->4 [2] ->4 ->6 ->8 [2]; every wait >=1.5-phase cover.

#define PHASE(A_, B_, MH, JX, NEWB, STAGE, WAITC)                             \
  {                                                                           \
    bf16x8 af[4];                                                             \
    if (NEWB) {                                                               \
      _Pragma("unroll") for (int ni = 0; ni < 4; ++ni)                        \
        bfr[ni] = *(const bf16x8*)((B_) + boff + (ni << 10) + (JX));          \
    }                                                                         \
    _Pragma("unroll") for (int mi = 0; mi < 4; ++mi)                          \
      af[mi] = *(const bf16x8*)((A_) + aoff + (((MH) * 4 + mi) << 10) + (JX));\
    STAGE                                                                     \
    asm volatile("" ::: "memory");                                            \
    __builtin_amdgcn_s_barrier();                                             \
    asm volatile("s_waitcnt lgkmcnt(0)" ::: "memory");                        \
    __builtin_amdgcn_sched_barrier(0);                                        \
    __builtin_amdgcn_s_setprio(1);                                            \
    _Pragma("unroll") for (int mi = 0; mi < 4; ++mi)                          \
      _Pragma("unroll") for (int ni = 0; ni < 4; ++ni)                        \
        acc[((MH) << 2) + mi][ni] = __builtin_amdgcn_mfma_f32_16x16x32_bf16(  \
            af[mi], bfr[ni], acc[((MH) << 2) + mi][ni], 0, 0, 0);             \
    __builtin_amdgcn_s_setprio(0);                                            \
    WAITC                                                                     \
    asm volatile("" ::: "memory");                                            \
    __builtin_amdgcn_s_barrier();                                             \
    asm volatile("" ::: "memory");                                            \
  }

#define TILE(P_, Q_, KOFF, ST_, LAST_)                                        \
  { const __bf16* A_ = &As[P_][0];                                            \
    const __bf16* B_ = &Bs[P_][0];                                            \
    bf16x8 bfr[4];                                                            \
    PHASE(A_, B_, 0, jx0, 1,                                                  \
      if (ST_) { glds16(gB[0] + (KOFF), lB##Q_[0]);                           \
                 glds16(gB[1] + (KOFF), lB##Q_[1]); },                        \
      if (LAST_) { asm volatile("s_waitcnt vmcnt(0)" ::: "memory"); }         \
      else       { asm volatile("s_waitcnt vmcnt(2)" ::: "memory"); })        \
    PHASE(A_, B_, 1, jx0, 0,                                                  \
      if (ST_) { glds16(gB[2] + (KOFF), lB##Q_[2]);                           \
                 glds16(gB[3] + (KOFF), lB##Q_[3]); }, )                      \
    PHASE(A_, B_, 0, jx1, 1,                                                  \
      if (ST_) { glds16(gA[0] + (KOFF), lA##Q_[0]);                           \
                 glds16(gA[2] + (KOFF), lA##Q_[2]); }, )                      \
    PHASE(A_, B_, 1, jx1, 0,                                                  \
      if (ST_) { glds16(gA[1] + (KOFF), lA##Q_[1]);                           \
                 glds16(gA[3] + (KOFF), lA##Q_[3]);                           \
                 asm volatile("s_waitcnt vmcnt(2)" ::: "memory"); }, )        \
  }

__global__ __launch_bounds__(512, 2) void gemm_bt(
    const __bf16* __restrict__ Xb, const __bf16* __restrict__ Wb,
    const float* __restrict__ bias, float* __restrict__ out) {
  __shared__ __align__(16) __bf16 As[2][256 * 64];
  __shared__ __align__(16) __bf16 Bs[2][256 * 64];

  const int tid  = threadIdx.x;
  const int wave = tid >> 6;
  const int lane = tid & 63;

  // XCD-rectangular swizzle (round-2, FETCH 745->355MB): each XCD owns a
  // 16bm x 5bn band walked as two 8x4 sub-rects + 5th column; 3 leftover
  // cols split across XCDs. Bijective over 688 blocks.
  const int orig = blockIdx.x;
  const int xcd  = orig & 7;
  const int slot = orig >> 3;          // 0..85
  int bm, bn;
  if (slot < 64) {
    bm = ((slot >> 5) << 3) + (slot & 7);
    bn = xcd * 5 + ((slot >> 3) & 3);
  } else if (slot < 80) {
    bm = slot - 64;
    bn = xcd * 5 + 4;
  } else {
    const int idx = xcd * 6 + (slot - 80);
    bm = idx & 15;
    bn = 40 + (idx >> 4);
  }
  const int m0 = bm << 8;
  const int n0 = bn << 8;

  const int wm = (wave >> 2) << 7;   // 0 or 128
  const int wn = (wave & 3) << 6;    // 0,64,128,192

  // cooperative staging: chunk c = r*512 + tid; row = c>>3 (A: rows r*64..);
  // LDS slot jl = c&7 holds global chunk j = jl ^ (row&7); LDS dest linear.
  const __bf16* gA[4]; const __bf16* gB[4];
  __bf16 *lA0[4], *lA1[4], *lB0[4], *lB1[4];
#pragma unroll
  for (int r = 0; r < 4; ++r) {
    const int c   = (r << 9) + tid;
    const int row = c >> 3;
    const int j   = (c & 7) ^ (row & 7);
    gA[r] = Xb + (size_t)(m0 + row) * INF + (j << 3);
    gB[r] = Wb + (size_t)(n0 + row) * INF + (j << 3);
    const int lbase = ((r << 9) + (wave << 6)) << 3;   // wave-uniform
    lA0[r] = &As[0][lbase]; lA1[r] = &As[1][lbase];
    lB0[r] = &Bs[0][lbase]; lB1[r] = &Bs[1][lbase];
  }

  floatx4 acc[8][4];
  const floatx4 z4 = {0.f, 0.f, 0.f, 0.f};
#pragma unroll
  for (int mi = 0; mi < 8; ++mi)
#pragma unroll
    for (int ni = 0; ni < 4; ++ni) acc[mi][ni] = z4;

  const int fr   = lane & 15;
  const int quad = lane >> 4;
  const int jx0  = ((0 * 4 + quad) ^ (fr & 7)) << 3;
  const int jx1  = ((1 * 4 + quad) ^ (fr & 7)) << 3;
  const int aoff = (wm + fr) << 6;
  const int boff = (wn + fr) << 6;

  // prologue: tile0 in steady-state issue order; vmcnt(2) leaves A1,A3 in
  // flight (first read at phase 2, published by tile0's end-p1 wait).
  glds16(gB[0], lB0[0]); glds16(gB[1], lB0[1]);
  glds16(gB[2], lB0[2]); glds16(gB[3], lB0[3]);
  glds16(gA[0], lA0[0]); glds16(gA[2], lA0[2]);
  glds16(gA[1], lA0[1]); glds16(gA[3], lA0[3]);
  asm volatile("s_waitcnt vmcnt(2)" ::: "memory");
  __builtin_amdgcn_s_barrier();
  asm volatile("" ::: "memory");

  // tiles 0..61 (stage t+1 / t+2), tile 62 (stages 63), tile 63 (no stage)
  for (int t = 0; t < 62; t += 2) {
    TILE(0, 1, ((t + 1) << 6), 1, 0)
    TILE(1, 0, ((t + 2) << 6), 1, 0)
  }
  TILE(0, 1, (63 << 6), 1, 0)
  TILE(1, 0, 0, 0, 1)

  // epilogue: C/D layout col = lane&15 (n), row = quad*4 + reg (m)
#pragma unroll
  for (int ni = 0; ni < 4; ++ni) {
    const int n = n0 + wn + (ni << 4) + fr;
    const float bv = bias[n];
#pragma unroll
    for (int mi = 0; mi < 8; ++mi) {
      const int mb = m0 + wm + (mi << 4) + (quad << 2);
#pragma unroll
      for (int j = 0; j < 4; ++j) {
        out[(size_t)(mb + j) * OUTF + n] = acc[mi][ni][j] + bv;
      }
    }
  }
}

extern "C" void kernel_launch(void* const* d_in, const int* in_sizes, int n_in,
                              void* d_out, int out_size, void* d_ws, size_t ws_size,
                              hipStream_t stream) {
  const float* x  = (const float*)d_in[0];   // [4096,4096] fp32
  const int*   Wq = (const int*)d_in[1];     // [32,704512] int32 (one byte each)
  const float* sc = (const float*)d_in[2];   // [704512]
  const float* zp = (const float*)d_in[3];   // [704512]
  const float* bs = (const float*)d_in[4];   // [11008]
  float* out = (float*)d_out;                // [4096,11008] fp32

  __bf16* Xb = (__bf16*)d_ws;                       // 32 MiB
  __bf16* Wb = Xb + (size_t)TOK * INF;              // 86 MiB

  convert_x_kernel<<<dim3((TOK * INF) / (256 * 8)), dim3(256), 0, stream>>>(x, Xb);
  dequant_w_kernel<<<dim3(32 * QD), dim3(256), 0, stream>>>(Wq, sc, zp, Wb);
  gemm_bt<<<dim3(OUTF / 256 * (TOK / 256)), dim3(512), 0, stream>>>(Xb, Wb, bs, out);
}